// Round 1
// baseline (727.112 us; speedup 1.0000x reference)
//
#include <hip/hip_runtime.h>
#include <stdint.h>

#define B_  4096
#define A_  14
#define QD_ 64
#define H_  12
#define CH_ 768
#define M_  (B_*A_)     // 57344
#define NS_ (H_*A_)     // 168
#define N1_ (CH_+NS_)   // 936

typedef float  f32x4  __attribute__((ext_vector_type(4)));
typedef short  bf16x8 __attribute__((ext_vector_type(8)));
typedef short  s16x4  __attribute__((ext_vector_type(4)));
typedef int    i32x4  __attribute__((ext_vector_type(4)));

__device__ __forceinline__ float b2f(ushort u) {
  union { uint32_t u; float f; } c; c.u = ((uint32_t)u) << 16; return c.f;
}
__device__ __forceinline__ ushort f2b(float f) {
  union { float f; uint32_t u; } c; c.f = f;
  uint32_t u = c.u;
  return (ushort)((u + 0x7FFFu + ((u >> 16) & 1u)) >> 16);  // RNE
}

// ---------------- prep kernels ----------------

// Q[a][q] = sum_d cq[a][d]*WQ[a][d][q] + bQ[a][q]   (14x64, one block)
__global__ void prep_q(const float* __restrict__ cq, const float* __restrict__ WQ,
                       const float* __restrict__ bQ, float* __restrict__ Qout) {
  for (int i = threadIdx.x; i < A_*QD_; i += 256) {
    int a = i >> 6, q = i & 63;
    float acc = bQ[i];
    for (int d = 0; d < 64; ++d) acc += cq[a*64 + d] * WQ[(a*64 + d)*64 + q];
    Qout[i] = acc;
  }
}

// Wcat (B^T layout, [1024 rows][768]): rows 0..767 = WV col (h*64+q); rows 768..935 =
// WS[h,a,:] = 0.125*sum_q Q[a,q]*WK[h,:,q]; rows 936..1023 = 0. biascat similarly.
__global__ void prep_wcat(const float* __restrict__ WV, const float* __restrict__ bV,
                          const float* __restrict__ WK, const float* __restrict__ bK,
                          const float* __restrict__ Qb, ushort* __restrict__ Wcat,
                          float* __restrict__ biascat) {
  int n = blockIdx.x, t = threadIdx.x;
  if (n < CH_) {
    int h = n >> 6, q = n & 63;
    for (int c = t; c < CH_; c += 256)
      Wcat[(size_t)n*CH_ + c] = f2b(WV[((size_t)h*CH_ + c)*64 + q]);
    if (t == 0) biascat[n] = bV[n];
  } else if (n < N1_) {
    int j = n - CH_; int h = j / 14, a = j % 14;
    __shared__ float qrow[64];
    if (t < 64) qrow[t] = Qb[a*64 + t];
    __syncthreads();
    for (int c = t; c < CH_; c += 256) {
      const float* wk = WK + ((size_t)h*CH_ + c)*64;
      float acc = 0.f;
      #pragma unroll
      for (int q = 0; q < 64; ++q) acc += qrow[q] * wk[q];
      Wcat[(size_t)n*CH_ + c] = f2b(acc * 0.125f);
    }
    if (t == 0) {
      float acc = 0.f;
      for (int q = 0; q < 64; ++q) acc += qrow[q] * bK[h*64 + q];
      biascat[n] = acc * 0.125f;
    }
  } else {
    for (int c = t; c < CH_; c += 256) Wcat[(size_t)n*CH_ + c] = 0;
    if (t == 0) biascat[n] = 0.f;
  }
}

// W1T/W2T: [768][768] bf16, transposed ([n][k] = W[k][n])
__global__ void prep_wt(const float* __restrict__ W1, const float* __restrict__ W2,
                        ushort* __restrict__ W1T, ushort* __restrict__ W2T) {
  int i = blockIdx.x;
  int n = (i < CH_) ? i : i - CH_;
  const float* W = (i < CH_) ? W1 : W2;
  ushort* O = (i < CH_) ? W1T : W2T;
  for (int k = threadIdx.x; k < CH_; k += 256)
    O[(size_t)n*CH_ + k] = f2b(W[(size_t)k*CH_ + n]);
}

// cls fp32 -> bf16
__global__ void prep_cls(const float* __restrict__ cls, ushort* __restrict__ out) {
  const size_t n4 = (size_t)M_*CH_/4;  // 11010048
  for (size_t i = (size_t)blockIdx.x*256 + threadIdx.x; i < n4; i += (size_t)gridDim.x*256) {
    const float* p = cls + i*4;
    s16x4 o;
    o[0] = (short)f2b(p[0]); o[1] = (short)f2b(p[1]);
    o[2] = (short)f2b(p[2]); o[3] = (short)f2b(p[3]);
    *(s16x4*)(out + i*4) = o;
  }
}

// ---------------- GEMM: C[M=57344, N] = A[M,768] * B^T[N,768], bf16 MFMA ----------------
// MODE 0: N=1024(pad of 936): cols<768 -> Vbuf bf16; 768..935 -> Sbuf fp32 scattered
// MODE 1: relu(x@W1+b1) -> bf16     MODE 2: h1@W2+b2 -> bf16
template<int MODE>
__global__ __launch_bounds__(256)
void gemm_k(const ushort* __restrict__ Ap, const ushort* __restrict__ Bp,
            const float* __restrict__ bias,
            ushort* __restrict__ Cb, float* __restrict__ Sout) {
  const int tid = threadIdx.x;
  const int wave = tid >> 6, lane = tid & 63;
  const int wm = wave >> 1, wn = wave & 1;          // 2x2 waves, 64x64 each
  const int m0 = blockIdx.y * 128, n0 = blockIdx.x * 128;

  __shared__ __align__(16) ushort Asm[128*64];
  __shared__ __align__(16) ushort Bsm[128*64];

  f32x4 acc[4][4] = {};

  const int srow0  = wave*32 + (lane >> 3);
  const int schunk = lane & 7;

  for (int kt = 0; kt < 12; ++kt) {
    const int k0 = kt * 64;
    #pragma unroll
    for (int i = 0; i < 4; ++i) {
      const int row = srow0 + i*8;
      const int dby = row*128 + ((schunk ^ (row & 7)) * 16);  // XOR-swizzled dest
      i32x4 av = *(const i32x4*)(Ap + (size_t)(m0 + row)*CH_ + k0 + schunk*8);
      i32x4 bv = *(const i32x4*)(Bp + (size_t)(n0 + row)*CH_ + k0 + schunk*8);
      *(i32x4*)((char*)Asm + dby) = av;
      *(i32x4*)((char*)Bsm + dby) = bv;
    }
    __syncthreads();
    #pragma unroll
    for (int kk = 0; kk < 2; ++kk) {
      bf16x8 af[4], bfr[4];
      #pragma unroll
      for (int f = 0; f < 4; ++f) {
        int ar = wm*64 + f*16 + (lane & 15);
        int ab = ar*128 + kk*64 + (lane >> 4)*16;
        ab ^= (ar & 7) << 4;
        af[f] = *(const bf16x8*)((const char*)Asm + ab);
        int br = wn*64 + f*16 + (lane & 15);
        int bb = br*128 + kk*64 + (lane >> 4)*16;
        bb ^= (br & 7) << 4;
        bfr[f] = *(const bf16x8*)((const char*)Bsm + bb);
      }
      #pragma unroll
      for (int i = 0; i < 4; ++i)
        #pragma unroll
        for (int j = 0; j < 4; ++j)
          acc[i][j] = __builtin_amdgcn_mfma_f32_16x16x32_bf16(af[i], bfr[j], acc[i][j], 0, 0, 0);
    }
    __syncthreads();
  }

  #pragma unroll
  for (int j = 0; j < 4; ++j) {
    const int gc = n0 + wn*64 + j*16 + (lane & 15);
    const float bv = bias[gc];
    #pragma unroll
    for (int i = 0; i < 4; ++i) {
      const int gr0 = m0 + wm*64 + i*16 + ((lane >> 4) << 2);
      #pragma unroll
      for (int r = 0; r < 4; ++r) {
        const float v = acc[i][j][r] + bv;
        const int gr = gr0 + r;
        if (MODE == 0) {
          if (gc < CH_) {
            Cb[(size_t)gr*CH_ + gc] = f2b(v);
          } else if (gc < N1_) {
            const int j2 = gc - CH_;
            const int h = j2 / 14, a = j2 % 14;
            const int b = gr / 14, s = gr % 14;
            Sout[(((size_t)b*H_ + h)*A_ + a)*A_ + s] = v;
          }
        } else if (MODE == 1) {
          Cb[(size_t)gr*CH_ + gc] = f2b(fmaxf(v, 0.f));
        } else {
          Cb[(size_t)gr*CH_ + gc] = f2b(v);
        }
      }
    }
  }
}

// ---------------- fused attention (softmax over 'a') + residual + LN1 ----------------
__global__ __launch_bounds__(256)
void attn_ln1(const float* __restrict__ Sbuf, const ushort* __restrict__ Vbuf,
              const float* __restrict__ cls, const float* __restrict__ g1,
              const float* __restrict__ be1, ushort* __restrict__ xout) {
  const int b = blockIdx.x, tid = threadIdx.x;
  const int wave = tid >> 6, lane = tid & 63;
  __shared__ __align__(16) float  s_sc[H_*A_*A_];     // 12*14*14 scores -> attn
  __shared__ __align__(16) ushort s_v[A_*CH_];        // 14*768 bf16
  __shared__ __align__(16) float  s_out[A_*CH_];      // 14*768 f32

  for (int i = tid; i < H_*A_*A_; i += 256) s_sc[i] = Sbuf[(size_t)b*H_*A_*A_ + i];
  for (int i = tid; i < A_*CH_/8; i += 256)   // 16B chunks
    *(i32x4*)((char*)s_v + i*16) = *(const i32x4*)((const char*)(Vbuf + (size_t)b*A_*CH_) + i*16);
  __syncthreads();

  if (tid < H_*A_) {           // softmax over a for each (h,s)
    int h = tid / 14, s = tid % 14;
    float vals[14], mx = -1e30f;
    #pragma unroll
    for (int a = 0; a < 14; ++a) { float v = s_sc[(h*14 + a)*14 + s]; vals[a] = v; mx = fmaxf(mx, v); }
    float sum = 0.f;
    #pragma unroll
    for (int a = 0; a < 14; ++a) { float e = __expf(vals[a] - mx); vals[a] = e; sum += e; }
    float inv = 1.f / sum;
    #pragma unroll
    for (int a = 0; a < 14; ++a) s_sc[(h*14 + a)*14 + s] = vals[a] * inv;
  }
  __syncthreads();

  // PV: out[a][c] = sum_s attn[h][a][s] * V[s][c], c-quads
  for (int idx = tid; idx < A_*(CH_/4); idx += 256) {
    int a = idx / (CH_/4), c = (idx % (CH_/4)) * 4;
    int h = c >> 6;
    const float* at = &s_sc[(h*14 + a)*14];
    float a0 = 0.f, a1 = 0.f, a2 = 0.f, a3 = 0.f;
    #pragma unroll
    for (int s = 0; s < 14; ++s) {
      float w = at[s];
      s16x4 vv = *(const s16x4*)(&s_v[s*CH_ + c]);
      a0 += w * b2f((ushort)vv[0]); a1 += w * b2f((ushort)vv[1]);
      a2 += w * b2f((ushort)vv[2]); a3 += w * b2f((ushort)vv[3]);
    }
    f32x4 st; st[0] = a0; st[1] = a1; st[2] = a2; st[3] = a3;
    *(f32x4*)(&s_out[a*CH_ + c]) = st;
  }
  __syncthreads();

  // LN per row: wave w handles rows w, w+4, w+8, w+12
  for (int a = wave; a < A_; a += 4) {
    const f32x4* crow = (const f32x4*)(cls + ((size_t)b*A_ + a)*CH_);
    f32x4 vr[3]; float sum = 0.f, sq = 0.f;
    #pragma unroll
    for (int j = 0; j < 3; ++j) {
      f32x4 cv = crow[lane + j*64];
      f32x4 ov = *(const f32x4*)(&s_out[a*CH_ + (lane + j*64)*4]);
      f32x4 t = cv + ov;
      vr[j] = t;
      #pragma unroll
      for (int u = 0; u < 4; ++u) { sum += t[u]; sq += t[u]*t[u]; }
    }
    #pragma unroll
    for (int off = 32; off >= 1; off >>= 1) {
      sum += __shfl_xor(sum, off, 64);
      sq  += __shfl_xor(sq,  off, 64);
    }
    float mean = sum * (1.f/768.f);
    float var  = sq * (1.f/768.f) - mean*mean;
    float rstd = rsqrtf(var + 1e-5f);
    #pragma unroll
    for (int j = 0; j < 3; ++j) {
      int c = (lane + j*64)*4;
      f32x4 gv = *(const f32x4*)(g1 + c);
      f32x4 bv = *(const f32x4*)(be1 + c);
      s16x4 pk;
      #pragma unroll
      for (int u = 0; u < 4; ++u)
        pk[u] = (short)f2b((vr[j][u] - mean)*rstd*gv[u] + bv[u]);
      *(s16x4*)(&xout[((size_t)b*A_ + a)*CH_ + c]) = pk;
    }
  }
}

// ---------------- final residual + LN2 -> fp32 out ----------------
__global__ __launch_bounds__(256)
void ln2_k(const ushort* __restrict__ xb, const ushort* __restrict__ yb,
           const float* __restrict__ g2, const float* __restrict__ be2,
           float* __restrict__ out) {
  const int row = blockIdx.x*4 + (threadIdx.x >> 6);
  const int lane = threadIdx.x & 63;
  const ushort* xr = xb + (size_t)row*CH_;
  const ushort* yr = yb + (size_t)row*CH_;
  float v[12]; float sum = 0.f, sq = 0.f;
  #pragma unroll
  for (int j = 0; j < 3; ++j) {
    int c = (lane + j*64)*4;
    s16x4 xv = *(const s16x4*)(xr + c);
    s16x4 yv = *(const s16x4*)(yr + c);
    #pragma unroll
    for (int u = 0; u < 4; ++u) {
      float t = b2f((ushort)xv[u]) + b2f((ushort)yv[u]);
      v[j*4 + u] = t; sum += t; sq += t*t;
    }
  }
  #pragma unroll
  for (int off = 32; off >= 1; off >>= 1) {
    sum += __shfl_xor(sum, off, 64);
    sq  += __shfl_xor(sq,  off, 64);
  }
  float mean = sum * (1.f/768.f);
  float var  = sq * (1.f/768.f) - mean*mean;
  float rstd = rsqrtf(var + 1e-5f);
  float* orow = out + (size_t)row*CH_;
  #pragma unroll
  for (int j = 0; j < 3; ++j) {
    int c = (lane + j*64)*4;
    f32x4 gv = *(const f32x4*)(g2 + c);
    f32x4 bv = *(const f32x4*)(be2 + c);
    f32x4 o;
    #pragma unroll
    for (int u = 0; u < 4; ++u) o[u] = (v[j*4+u] - mean)*rstd*gv[u] + bv[u];
    *(f32x4*)(orow + c) = o;
  }
}

// ---------------- launch ----------------
extern "C" void kernel_launch(void* const* d_in, const int* in_sizes, int n_in,
                              void* d_out, int out_size, void* d_ws, size_t ws_size,
                              hipStream_t stream) {
  const float* cq  = (const float*)d_in[0];
  const float* cls = (const float*)d_in[1];
  const float* WQ  = (const float*)d_in[2];
  const float* bQ  = (const float*)d_in[3];
  const float* WK  = (const float*)d_in[4];
  const float* bK  = (const float*)d_in[5];
  const float* WV  = (const float*)d_in[6];
  const float* bV  = (const float*)d_in[7];
  const float* W1  = (const float*)d_in[8];
  const float* b1  = (const float*)d_in[9];
  const float* W2  = (const float*)d_in[10];
  const float* b2  = (const float*)d_in[11];
  const float* g1  = (const float*)d_in[12];
  const float* be1 = (const float*)d_in[13];
  const float* g2  = (const float*)d_in[14];
  const float* be2 = (const float*)d_in[15];
  float* out = (float*)d_out;

  char* ws = (char*)d_ws;
  float*  qbuf    = (float*)(ws + 0);            // 3,584
  float*  biascat = (float*)(ws + 4096);         // 4,096
  ushort* wcat    = (ushort*)(ws + 8192);        // 1,572,864  [1024][768]
  ushort* w1t     = (ushort*)(ws + 1581056);     // 1,179,648
  ushort* w2t     = (ushort*)(ws + 2760704);     // 1,179,648
  ushort* clsbf   = (ushort*)(ws + 4194304);     // 88,080,384  R1 (later xbuf)
  ushort* vbuf    = (ushort*)(ws + 92274688);    // 88,080,384  R2 (later h1)
  float*  sbuf    = (float*)(ws + 180355072);    // 38,535,168  R3
  ushort* ybuf    = (ushort*)(ws + 218890240);   // 88,080,384  R4
  ushort* xbuf  = clsbf;   // R1 reuse: clsbf dead after gemm<0>
  ushort* h1buf = vbuf;    // R2 reuse: vbuf dead after attn_ln1

  prep_q   <<<1,    256, 0, stream>>>(cq, WQ, bQ, qbuf);
  prep_wcat<<<1024, 256, 0, stream>>>(WV, bV, WK, bK, qbuf, wcat, biascat);
  prep_wt  <<<1536, 256, 0, stream>>>(W1, W2, w1t, w2t);
  prep_cls <<<2048, 256, 0, stream>>>(cls, clsbf);

  gemm_k<0><<<dim3(8, 448), 256, 0, stream>>>(clsbf, wcat, biascat, vbuf, sbuf);
  attn_ln1 <<<B_, 256, 0, stream>>>(sbuf, vbuf, cls, g1, be1, xbuf);
  gemm_k<1><<<dim3(6, 448), 256, 0, stream>>>(xbuf, w1t, b1, h1buf, nullptr);
  gemm_k<2><<<dim3(6, 448), 256, 0, stream>>>(h1buf, w2t, b2, ybuf, nullptr);
  ln2_k    <<<M_/4, 256, 0, stream>>>(xbuf, ybuf, g2, be2, out);
}

// Round 2
// 669.829 us; speedup vs baseline: 1.0855x; 1.0855x over previous
//
#include <hip/hip_runtime.h>
#include <stdint.h>

#define B_  4096
#define A_  14
#define QD_ 64
#define H_  12
#define CH_ 768
#define M_  (B_*A_)     // 57344
#define NS_ (H_*A_)     // 168
#define N1_ (CH_+NS_)   // 936

typedef float  f32x4  __attribute__((ext_vector_type(4)));
typedef short  bf16x8 __attribute__((ext_vector_type(8)));
typedef short  s16x4  __attribute__((ext_vector_type(4)));
typedef int    i32x4  __attribute__((ext_vector_type(4)));

#define GLOAD_LDS16(gp, lp) \
  __builtin_amdgcn_global_load_lds((const __attribute__((address_space(1))) void*)(gp), \
                                   (__attribute__((address_space(3))) void*)(lp), 16, 0, 0)

__device__ __forceinline__ float b2f(ushort u) {
  union { uint32_t u; float f; } c; c.u = ((uint32_t)u) << 16; return c.f;
}
__device__ __forceinline__ ushort f2b(float f) {
  union { float f; uint32_t u; } c; c.f = f;
  uint32_t u = c.u;
  return (ushort)((u + 0x7FFFu + ((u >> 16) & 1u)) >> 16);  // RNE
}

// ---------------- prep kernels ----------------

__global__ void prep_q(const float* __restrict__ cq, const float* __restrict__ WQ,
                       const float* __restrict__ bQ, float* __restrict__ Qout) {
  for (int i = threadIdx.x; i < A_*QD_; i += 256) {
    int a = i >> 6, q = i & 63;
    float acc = bQ[i];
    for (int d = 0; d < 64; ++d) acc += cq[a*64 + d] * WQ[(a*64 + d)*64 + q];
    Qout[i] = acc;
  }
}

// Wcat (B^T layout, [1024 rows][768]): rows 0..767 = WV col (h*64+q); rows 768..935 =
// WS[h,a,:] = 0.125*sum_q Q[a,q]*WK[h,:,q]; rows 936..1023 = 0.
__global__ void prep_wcat(const float* __restrict__ WV, const float* __restrict__ bV,
                          const float* __restrict__ WK, const float* __restrict__ bK,
                          const float* __restrict__ Qb, ushort* __restrict__ Wcat,
                          float* __restrict__ biascat) {
  int n = blockIdx.x, t = threadIdx.x;
  if (n < CH_) {
    int h = n >> 6, q = n & 63;
    for (int c = t; c < CH_; c += 256)
      Wcat[(size_t)n*CH_ + c] = f2b(WV[((size_t)h*CH_ + c)*64 + q]);
    if (t == 0) biascat[n] = bV[n];
  } else if (n < N1_) {
    int j = n - CH_; int h = j / 14, a = j % 14;
    __shared__ float qrow[64];
    if (t < 64) qrow[t] = Qb[a*64 + t];
    __syncthreads();
    for (int c = t; c < CH_; c += 256) {
      const float* wk = WK + ((size_t)h*CH_ + c)*64;
      float acc = 0.f;
      #pragma unroll
      for (int q = 0; q < 64; ++q) acc += qrow[q] * wk[q];
      Wcat[(size_t)n*CH_ + c] = f2b(acc * 0.125f);
    }
    if (t == 0) {
      float acc = 0.f;
      for (int q = 0; q < 64; ++q) acc += qrow[q] * bK[h*64 + q];
      biascat[n] = acc * 0.125f;
    }
  } else {
    for (int c = t; c < CH_; c += 256) Wcat[(size_t)n*CH_ + c] = 0;
    if (t == 0) biascat[n] = 0.f;
  }
}

__global__ void prep_wt(const float* __restrict__ W1, const float* __restrict__ W2,
                        ushort* __restrict__ W1T, ushort* __restrict__ W2T) {
  int i = blockIdx.x;
  int n = (i < CH_) ? i : i - CH_;
  const float* W = (i < CH_) ? W1 : W2;
  ushort* O = (i < CH_) ? W1T : W2T;
  for (int k = threadIdx.x; k < CH_; k += 256)
    O[(size_t)n*CH_ + k] = f2b(W[(size_t)k*CH_ + n]);
}

__global__ void prep_cls(const float* __restrict__ cls, ushort* __restrict__ out) {
  const size_t n4 = (size_t)M_*CH_/4;
  for (size_t i = (size_t)blockIdx.x*256 + threadIdx.x; i < n4; i += (size_t)gridDim.x*256) {
    const float* p = cls + i*4;
    s16x4 o;
    o[0] = (short)f2b(p[0]); o[1] = (short)f2b(p[1]);
    o[2] = (short)f2b(p[2]); o[3] = (short)f2b(p[3]);
    *(s16x4*)(out + i*4) = o;
  }
}

// ---------------- GEMM: C[M, N] = A[M,768] * B^T[N,768], bf16 MFMA ----------------
// global_load_lds(16B) staging, linear LDS dest, inverse-swizzled global source,
// XOR-swizzled ds_read (rule #21). XCD-aware bijective block remap (T1).
// MODE 0: N=1024(pad of 936): cols<768 -> Vbuf bf16; 768..935 -> Sbuf fp32 scattered
// MODE 1: relu(x@W1+b1) -> bf16     MODE 2: h1@W2+b2 -> bf16
template<int MODE>
__global__ __launch_bounds__(256)
void gemm_k(const ushort* __restrict__ Ap, const ushort* __restrict__ Bp,
            const float* __restrict__ bias,
            ushort* __restrict__ Cb, float* __restrict__ Sout) {
  constexpr int GX = (MODE == 0) ? 8 : 6;
  constexpr int NWG = GX * 448;
  const int tid = threadIdx.x;
  const int wave = tid >> 6, lane = tid & 63;
  const int wm = wave >> 1, wn = wave & 1;          // 2x2 waves, 64x64 each

  // XCD remap: blocks with bid%8==j dispatch to XCD j; give each XCD a
  // contiguous tile range, N-fastest -> A-panel reused within one L2.
  const int bid = blockIdx.x;
  const int tl = (bid & 7) * (NWG >> 3) + (bid >> 3);
  const int m0 = (tl / GX) * 128, n0 = (tl % GX) * 128;

  __shared__ __align__(16) ushort Asm[128*64];
  __shared__ __align__(16) ushort Bsm[128*64];

  f32x4 acc[4][4] = {};

  // staging geometry: instruction c writes LDS bytes [c*1024, c*1024+1024):
  // lane l -> row c*8 + (l>>3), 16B-chunk (l&7). Source chunk inverse-swizzled.
  const int rc = lane >> 3;            // row within 8-row group
  const int sc = (lane & 7) ^ rc;      // global source chunk (16B units)
  const ushort* Abase = Ap + (size_t)(m0 + rc)*CH_ + sc*8;
  const ushort* Bbase = Bp + (size_t)(n0 + rc)*CH_ + sc*8;

  for (int kt = 0; kt < 12; ++kt) {
    const int k0 = kt * 64;
    #pragma unroll
    for (int ci = 0; ci < 4; ++ci) {
      const int c = wave*4 + ci;
      GLOAD_LDS16(Abase + (size_t)c*8*CH_ + k0, &Asm[c*512]);
      GLOAD_LDS16(Bbase + (size_t)c*8*CH_ + k0, &Bsm[c*512]);
    }
    __syncthreads();   // compiler emits vmcnt(0) drain before barrier
    #pragma unroll
    for (int kk = 0; kk < 2; ++kk) {
      bf16x8 af[4], bfr[4];
      #pragma unroll
      for (int f = 0; f < 4; ++f) {
        int ar = wm*64 + f*16 + (lane & 15);
        int ab = (ar*128 + kk*64 + (lane >> 4)*16) ^ ((ar & 7) << 4);
        af[f] = *(const bf16x8*)((const char*)Asm + ab);
        int br = wn*64 + f*16 + (lane & 15);
        int bb = (br*128 + kk*64 + (lane >> 4)*16) ^ ((br & 7) << 4);
        bfr[f] = *(const bf16x8*)((const char*)Bsm + bb);
      }
      #pragma unroll
      for (int i = 0; i < 4; ++i)
        #pragma unroll
        for (int j = 0; j < 4; ++j)
          acc[i][j] = __builtin_amdgcn_mfma_f32_16x16x32_bf16(af[i], bfr[j], acc[i][j], 0, 0, 0);
    }
    __syncthreads();
  }

  #pragma unroll
  for (int j = 0; j < 4; ++j) {
    const int gc = n0 + wn*64 + j*16 + (lane & 15);
    const float bv = bias[gc];
    #pragma unroll
    for (int i = 0; i < 4; ++i) {
      const int gr0 = m0 + wm*64 + i*16 + ((lane >> 4) << 2);
      #pragma unroll
      for (int r = 0; r < 4; ++r) {
        const float v = acc[i][j][r] + bv;
        const int gr = gr0 + r;
        if (MODE == 0) {
          if (gc < CH_) {
            Cb[(size_t)gr*CH_ + gc] = f2b(v);
          } else if (gc < N1_) {
            const int j2 = gc - CH_;
            const int h = j2 / 14, a = j2 % 14;
            const int b = gr / 14, s = gr % 14;
            Sout[(((size_t)b*H_ + h)*A_ + a)*A_ + s] = v;
          }
        } else if (MODE == 1) {
          Cb[(size_t)gr*CH_ + gc] = f2b(fmaxf(v, 0.f));
        } else {
          Cb[(size_t)gr*CH_ + gc] = f2b(v);
        }
      }
    }
  }
}

// ---------------- fused attention (softmax over 'a') + residual + LN1 ----------------
// PV fused straight into LN registers: no s_out buffer -> LDS 31KB, 5 blocks/CU.
__global__ __launch_bounds__(256)
void attn_ln1(const float* __restrict__ Sbuf, const ushort* __restrict__ Vbuf,
              const float* __restrict__ cls, const float* __restrict__ g1,
              const float* __restrict__ be1, ushort* __restrict__ xout) {
  const int b = blockIdx.x, tid = threadIdx.x;
  const int wave = tid >> 6, lane = tid & 63;
  __shared__ __align__(16) float  s_sc[H_*A_*A_];     // 9408 B
  __shared__ __align__(16) ushort s_v[A_*CH_];        // 21504 B

  for (int i = tid; i < H_*A_*A_; i += 256) s_sc[i] = Sbuf[(size_t)b*H_*A_*A_ + i];
  for (int i = tid; i < A_*CH_/8; i += 256)
    *(i32x4*)((char*)s_v + i*16) = *(const i32x4*)((const char*)(Vbuf + (size_t)b*A_*CH_) + i*16);
  __syncthreads();

  if (tid < H_*A_) {           // softmax over a for each (h,s)
    int h = tid / 14, s = tid % 14;
    float vals[14], mx = -1e30f;
    #pragma unroll
    for (int a = 0; a < 14; ++a) { float v = s_sc[(h*14 + a)*14 + s]; vals[a] = v; mx = fmaxf(mx, v); }
    float sum = 0.f;
    #pragma unroll
    for (int a = 0; a < 14; ++a) { float e = __expf(vals[a] - mx); vals[a] = e; sum += e; }
    float inv = 1.f / sum;
    #pragma unroll
    for (int a = 0; a < 14; ++a) s_sc[(h*14 + a)*14 + s] = vals[a] * inv;
  }
  __syncthreads();

  // per-row: PV + residual + LN, all in registers. wave w -> rows w, w+4, w+8, w+12
  for (int a = wave; a < A_; a += 4) {
    f32x4 vr[3]; float sum = 0.f, sq = 0.f;
    #pragma unroll
    for (int j = 0; j < 3; ++j) {
      const int c = (lane + j*64) * 4;
      const int h = c >> 6;
      const float* at = &s_sc[(h*14 + a)*14];
      f32x4 acc = {};
      #pragma unroll
      for (int s = 0; s < 14; ++s) {
        float w = at[s];
        s16x4 vv = *(const s16x4*)(&s_v[s*CH_ + c]);
        acc[0] += w * b2f((ushort)vv[0]); acc[1] += w * b2f((ushort)vv[1]);
        acc[2] += w * b2f((ushort)vv[2]); acc[3] += w * b2f((ushort)vv[3]);
      }
      f32x4 cv = *(const f32x4*)(cls + ((size_t)b*A_ + a)*CH_ + c);
      f32x4 t = cv + acc;
      vr[j] = t;
      #pragma unroll
      for (int u = 0; u < 4; ++u) { sum += t[u]; sq += t[u]*t[u]; }
    }
    #pragma unroll
    for (int off = 32; off >= 1; off >>= 1) {
      sum += __shfl_xor(sum, off, 64);
      sq  += __shfl_xor(sq,  off, 64);
    }
    float mean = sum * (1.f/768.f);
    float var  = sq * (1.f/768.f) - mean*mean;
    float rstd = rsqrtf(var + 1e-5f);
    #pragma unroll
    for (int j = 0; j < 3; ++j) {
      int c = (lane + j*64)*4;
      f32x4 gv = *(const f32x4*)(g1 + c);
      f32x4 bv = *(const f32x4*)(be1 + c);
      s16x4 pk;
      #pragma unroll
      for (int u = 0; u < 4; ++u)
        pk[u] = (short)f2b((vr[j][u] - mean)*rstd*gv[u] + bv[u]);
      *(s16x4*)(&xout[((size_t)b*A_ + a)*CH_ + c]) = pk;
    }
  }
}

// ---------------- final residual + LN2 -> fp32 out ----------------
__global__ __launch_bounds__(256)
void ln2_k(const ushort* __restrict__ xb, const ushort* __restrict__ yb,
           const float* __restrict__ g2, const float* __restrict__ be2,
           float* __restrict__ out) {
  const int row = blockIdx.x*4 + (threadIdx.x >> 6);
  const int lane = threadIdx.x & 63;
  const ushort* xr = xb + (size_t)row*CH_;
  const ushort* yr = yb + (size_t)row*CH_;
  float v[12]; float sum = 0.f, sq = 0.f;
  #pragma unroll
  for (int j = 0; j < 3; ++j) {
    int c = (lane + j*64)*4;
    s16x4 xv = *(const s16x4*)(xr + c);
    s16x4 yv = *(const s16x4*)(yr + c);
    #pragma unroll
    for (int u = 0; u < 4; ++u) {
      float t = b2f((ushort)xv[u]) + b2f((ushort)yv[u]);
      v[j*4 + u] = t; sum += t; sq += t*t;
    }
  }
  #pragma unroll
  for (int off = 32; off >= 1; off >>= 1) {
    sum += __shfl_xor(sum, off, 64);
    sq  += __shfl_xor(sq,  off, 64);
  }
  float mean = sum * (1.f/768.f);
  float var  = sq * (1.f/768.f) - mean*mean;
  float rstd = rsqrtf(var + 1e-5f);
  float* orow = out + (size_t)row*CH_;
  #pragma unroll
  for (int j = 0; j < 3; ++j) {
    int c = (lane + j*64)*4;
    f32x4 gv = *(const f32x4*)(g2 + c);
    f32x4 bv = *(const f32x4*)(be2 + c);
    f32x4 o;
    #pragma unroll
    for (int u = 0; u < 4; ++u) o[u] = (v[j*4+u] - mean)*rstd*gv[u] + bv[u];
    *(f32x4*)(orow + c) = o;
  }
}

// ---------------- launch ----------------
extern "C" void kernel_launch(void* const* d_in, const int* in_sizes, int n_in,
                              void* d_out, int out_size, void* d_ws, size_t ws_size,
                              hipStream_t stream) {
  const float* cq  = (const float*)d_in[0];
  const float* cls = (const float*)d_in[1];
  const float* WQ  = (const float*)d_in[2];
  const float* bQ  = (const float*)d_in[3];
  const float* WK  = (const float*)d_in[4];
  const float* bK  = (const float*)d_in[5];
  const float* WV  = (const float*)d_in[6];
  const float* bV  = (const float*)d_in[7];
  const float* W1  = (const float*)d_in[8];
  const float* b1  = (const float*)d_in[9];
  const float* W2  = (const float*)d_in[10];
  const float* b2  = (const float*)d_in[11];
  const float* g1  = (const float*)d_in[12];
  const float* be1 = (const float*)d_in[13];
  const float* g2  = (const float*)d_in[14];
  const float* be2 = (const float*)d_in[15];
  float* out = (float*)d_out;

  char* ws = (char*)d_ws;
  float*  qbuf    = (float*)(ws + 0);            // 3,584
  float*  biascat = (float*)(ws + 4096);         // 4,096
  ushort* wcat    = (ushort*)(ws + 8192);        // 1,572,864  [1024][768]
  ushort* w1t     = (ushort*)(ws + 1581056);     // 1,179,648
  ushort* w2t     = (ushort*)(ws + 2760704);     // 1,179,648
  ushort* clsbf   = (ushort*)(ws + 4194304);     // 88,080,384  R1 (later xbuf)
  ushort* vbuf    = (ushort*)(ws + 92274688);    // 88,080,384  R2 (later h1)
  float*  sbuf    = (float*)(ws + 180355072);    // 38,535,168  R3
  ushort* ybuf    = (ushort*)(ws + 218890240);   // 88,080,384  R4
  ushort* xbuf  = clsbf;   // R1 reuse: clsbf dead after gemm<0>
  ushort* h1buf = vbuf;    // R2 reuse: vbuf dead after attn_ln1

  prep_q   <<<1,    256, 0, stream>>>(cq, WQ, bQ, qbuf);
  prep_wcat<<<1024, 256, 0, stream>>>(WV, bV, WK, bK, qbuf, wcat, biascat);
  prep_wt  <<<1536, 256, 0, stream>>>(W1, W2, w1t, w2t);
  prep_cls <<<2048, 256, 0, stream>>>(cls, clsbf);

  gemm_k<0><<<8*448, 256, 0, stream>>>(clsbf, wcat, biascat, vbuf, sbuf);
  attn_ln1 <<<B_, 256, 0, stream>>>(sbuf, vbuf, cls, g1, be1, xbuf);
  gemm_k<1><<<6*448, 256, 0, stream>>>(xbuf, w1t, b1, h1buf, nullptr);
  gemm_k<2><<<6*448, 256, 0, stream>>>(h1buf, w2t, b2, ybuf, nullptr);
  ln2_k    <<<M_/4, 256, 0, stream>>>(xbuf, ybuf, g2, be2, out);
}